// Round 1
// baseline (849.846 us; speedup 1.0000x reference)
//
#include <hip/hip_runtime.h>
#include <cstdint>

// ---------------- CSR build ----------------

__global__ __launch_bounds__(256) void k_count(const int* __restrict__ dst, int E, int* __restrict__ deg) {
    int i = blockIdx.x * 256 + threadIdx.x;
    if (i < E) atomicAdd(&deg[dst[i]], 1);
}

__global__ __launch_bounds__(256) void k_dinv(const int* __restrict__ deg, float* __restrict__ dinv, int n) {
    int i = blockIdx.x * 256 + threadIdx.x;
    if (i < n) dinv[i] = rsqrtf((float)deg[i] + 1.0f);  // +1 = self loop
}

// 3-kernel exclusive scan over deg[n] (n <= 128*1024)
__global__ __launch_bounds__(256) void k_scanA(const int* __restrict__ deg, int n, int* __restrict__ bsum) {
    __shared__ int red[256];
    int t = threadIdx.x;
    int base = blockIdx.x * 1024 + t * 4;
    int s = 0;
#pragma unroll
    for (int j = 0; j < 4; j++) { int idx = base + j; s += (idx < n) ? deg[idx] : 0; }
    red[t] = s; __syncthreads();
    for (int off = 128; off > 0; off >>= 1) { if (t < off) red[t] += red[t + off]; __syncthreads(); }
    if (t == 0) bsum[blockIdx.x] = red[0];
}

__global__ __launch_bounds__(128) void k_scanB(int* __restrict__ bsum, int nb) {
    __shared__ int sh[128];
    int t = threadIdx.x;
    int v = (t < nb) ? bsum[t] : 0;
    sh[t] = v; __syncthreads();
    for (int off = 1; off < 128; off <<= 1) {
        int x = (t >= off) ? sh[t - off] : 0;
        __syncthreads();
        sh[t] += x;
        __syncthreads();
    }
    if (t < nb) bsum[t] = sh[t] - v;  // exclusive
}

__global__ __launch_bounds__(256) void k_scanC(const int* __restrict__ deg, int n, const int* __restrict__ bsum,
                                               int* __restrict__ rowptr, int* __restrict__ cursor, int E) {
    __shared__ int sh[256];
    int t = threadIdx.x;
    int base = blockIdx.x * 1024 + t * 4;
    int v[4], pre[4]; int s = 0;
#pragma unroll
    for (int j = 0; j < 4; j++) { int idx = base + j; v[j] = (idx < n) ? deg[idx] : 0; pre[j] = s; s += v[j]; }
    sh[t] = s; __syncthreads();
    int own = s;
    for (int off = 1; off < 256; off <<= 1) {
        int x = (t >= off) ? sh[t - off] : 0;
        __syncthreads();
        sh[t] += x;
        __syncthreads();
    }
    int toff = sh[t] - own + bsum[blockIdx.x];
#pragma unroll
    for (int j = 0; j < 4; j++) {
        int idx = base + j;
        if (idx < n) { int rp = toff + pre[j]; rowptr[idx] = rp; cursor[idx] = rp; }
    }
    if (blockIdx.x == 0 && t == 0) rowptr[n] = E;
}

__global__ __launch_bounds__(256) void k_fill(const int* __restrict__ src, const int* __restrict__ dst, int E,
                                              const float* __restrict__ dinv, int* __restrict__ cursor,
                                              int* __restrict__ col, float* __restrict__ wn) {
    int i = blockIdx.x * 256 + threadIdx.x;
    if (i < E) {
        int u = src[i], v = dst[i];
        int pos = atomicAdd(&cursor[v], 1);
        col[pos] = u;
        wn[pos] = dinv[u];  // norm = dinv[src]*dinv[dst]; dinv[dst] applied at reduce epilogue
    }
}

// ---------------- GEMMs (fp32 vector) ----------------

// C[n][128] = A[n][128] @ W[128][128]. Block: 256 rows x 64 cols (blockIdx.y selects col half).
__global__ __launch_bounds__(256) void k_gemm_xw(const float* __restrict__ A, const float* __restrict__ W,
                                                 float* __restrict__ C, int n) {
    __shared__ float At[256][33];
    int t = threadIdx.x;
    int r0 = blockIdx.x * 256;
    int c0 = blockIdx.y * 64;
    int row = r0 + t;
    float acc[64];
#pragma unroll
    for (int c = 0; c < 64; c++) acc[c] = 0.f;

    for (int k0 = 0; k0 < 128; k0 += 32) {
        __syncthreads();
#pragma unroll
        for (int j = 0; j < 8; j++) {
            int q = t + 256 * j;          // 0..2047 float4 slots
            int ri = q >> 3;              // row in tile
            int kk = (q & 7) * 4;         // k within tile
            int gr = r0 + ri; if (gr >= n) gr = n - 1;
            const float4 vv = *(const float4*)(A + (size_t)gr * 128 + k0 + kk);
            At[ri][kk + 0] = vv.x; At[ri][kk + 1] = vv.y; At[ri][kk + 2] = vv.z; At[ri][kk + 3] = vv.w;
        }
        __syncthreads();
#pragma unroll
        for (int kk = 0; kk < 32; kk++) {
            float a = At[t][kk];
            const float* wr = W + (size_t)(k0 + kk) * 128 + c0;  // uniform -> s_load
#pragma unroll
            for (int c = 0; c < 64; c++) acc[c] = fmaf(a, wr[c], acc[c]);
        }
    }
    if (row < n) {
        float* crow = C + (size_t)row * 128 + c0;
#pragma unroll
        for (int c = 0; c < 64; c += 4) {
            float4 vv = { acc[c], acc[c + 1], acc[c + 2], acc[c + 3] };
            *(float4*)(crow + c) = vv;
        }
    }
}

// C[n][8] = A[n][128] @ W[128][8]
__global__ __launch_bounds__(256) void k_gemm_w3(const float* __restrict__ A, const float* __restrict__ W,
                                                 float* __restrict__ C, int n) {
    __shared__ float At[256][33];
    int t = threadIdx.x;
    int r0 = blockIdx.x * 256;
    int row = r0 + t;
    float acc[8];
#pragma unroll
    for (int c = 0; c < 8; c++) acc[c] = 0.f;

    for (int k0 = 0; k0 < 128; k0 += 32) {
        __syncthreads();
#pragma unroll
        for (int j = 0; j < 8; j++) {
            int q = t + 256 * j;
            int ri = q >> 3;
            int kk = (q & 7) * 4;
            int gr = r0 + ri; if (gr >= n) gr = n - 1;
            const float4 vv = *(const float4*)(A + (size_t)gr * 128 + k0 + kk);
            At[ri][kk + 0] = vv.x; At[ri][kk + 1] = vv.y; At[ri][kk + 2] = vv.z; At[ri][kk + 3] = vv.w;
        }
        __syncthreads();
#pragma unroll
        for (int kk = 0; kk < 32; kk++) {
            float a = At[t][kk];
            const float* wr = W + (size_t)(k0 + kk) * 8;  // uniform -> s_load
#pragma unroll
            for (int c = 0; c < 8; c++) acc[c] = fmaf(a, wr[c], acc[c]);
        }
    }
    if (row < n) {
        float* crow = C + (size_t)row * 8;
        float4 v0 = { acc[0], acc[1], acc[2], acc[3] };
        float4 v1 = { acc[4], acc[5], acc[6], acc[7] };
        *(float4*)(crow) = v0;
        *(float4*)(crow + 4) = v1;
    }
}

// ---------------- Aggregation (gather) ----------------

// F=128: one wave per node, lane = 2 features (float2). out = dinv[v]*sum + dinv[v]^2*self + b, ReLU.
__global__ __launch_bounds__(256) void k_agg128(const float* __restrict__ T, const int* __restrict__ rowptr,
                                                const int* __restrict__ col, const float* __restrict__ wn,
                                                const float* __restrict__ dinv, const float* __restrict__ bias,
                                                float* __restrict__ H, int n) {
    int wid = threadIdx.x >> 6, lane = threadIdx.x & 63;
    int v = blockIdx.x * 4 + wid;
    if (v >= n) return;
    int e0 = rowptr[v], e1 = rowptr[v + 1];
    const float2* Tp = (const float2*)T;
    float ax = 0.f, ay = 0.f;
    for (int e = e0; e < e1; e++) {
        int u = col[e];       // wave-uniform -> s_load
        float w = wn[e];
        float2 tv = Tp[(size_t)u * 64 + lane];   // coalesced 512B per wave
        ax = fmaf(w, tv.x, ax);
        ay = fmaf(w, tv.y, ay);
    }
    float dv = dinv[v];
    float2 sv = Tp[(size_t)v * 64 + lane];
    float2 bb = ((const float2*)bias)[lane];
    float ox = fmaf(dv, ax, dv * dv * sv.x) + bb.x;
    float oy = fmaf(dv, ay, dv * dv * sv.y) + bb.y;
    ox = ox > 0.f ? ox : 0.f;
    oy = oy > 0.f ? oy : 0.f;
    ((float2*)H)[(size_t)v * 64 + lane] = make_float2(ox, oy);
}

// F=8: thread per (node, feature)
__global__ __launch_bounds__(256) void k_agg8(const float* __restrict__ T, const int* __restrict__ rowptr,
                                              const int* __restrict__ col, const float* __restrict__ wn,
                                              const float* __restrict__ dinv, const float* __restrict__ bias,
                                              float* __restrict__ H, int n) {
    int gid = blockIdx.x * 256 + threadIdx.x;
    int v = gid >> 3, f = gid & 7;
    if (v >= n) return;
    int e0 = rowptr[v], e1 = rowptr[v + 1];
    float acc = 0.f;
    for (int e = e0; e < e1; e++) {
        acc = fmaf(wn[e], T[(size_t)col[e] * 8 + f], acc);
    }
    float dv = dinv[v];
    float o = fmaf(dv, acc, dv * dv * T[(size_t)v * 8 + f]) + bias[f];
    H[(size_t)v * 8 + f] = o > 0.f ? o : 0.f;
}

// out[n][16] = H[n][8] @ Wc[8][16] + bc. Thread per (node, 2 cols).
__global__ __launch_bounds__(256) void k_out(const float* __restrict__ H, const float* __restrict__ Wc,
                                             const float* __restrict__ bc, float* __restrict__ out, int n) {
    int gid = blockIdx.x * 256 + threadIdx.x;
    int v = gid >> 3, cp = (gid & 7) * 2;
    if (v >= n) return;
    float a0 = bc[cp], a1 = bc[cp + 1];
#pragma unroll
    for (int k = 0; k < 8; k++) {
        float h = H[(size_t)v * 8 + k];
        a0 = fmaf(h, Wc[k * 16 + cp], a0);
        a1 = fmaf(h, Wc[k * 16 + cp + 1], a1);
    }
    ((float2*)out)[(size_t)v * 8 + (cp >> 1)] = make_float2(a0, a1);
}

// ---------------- launch ----------------

extern "C" void kernel_launch(void* const* d_in, const int* in_sizes, int n_in,
                              void* d_out, int out_size, void* d_ws, size_t ws_size,
                              hipStream_t stream) {
    const float* x  = (const float*)d_in[0];
    const int*   ei = (const int*)d_in[1];
    const float* W1 = (const float*)d_in[2];
    const float* b1 = (const float*)d_in[3];
    const float* W2 = (const float*)d_in[4];
    const float* b2 = (const float*)d_in[5];
    const float* W3 = (const float*)d_in[6];
    const float* b3 = (const float*)d_in[7];
    const float* Wc = (const float*)d_in[8];
    const float* bc = (const float*)d_in[9];

    const int n = in_sizes[0] / 128;
    const int E = in_sizes[1] / 2;
    const int* src = ei;
    const int* dst = ei + E;

    char* p = (char*)d_ws;
    auto carve = [&](size_t bytes) -> char* {
        char* r = p;
        p += (bytes + 511) & ~(size_t)511;
        return r;
    };
    int*   deg    = (int*)  carve((size_t)n * 4);
    int*   cursor = (int*)  carve((size_t)n * 4);
    int*   rowptr = (int*)  carve((size_t)(n + 1) * 4);
    int*   bsum   = (int*)  carve(4096);
    float* dinv   = (float*)carve((size_t)n * 4);
    int*   col    = (int*)  carve((size_t)E * 4);
    float* wnv    = (float*)carve((size_t)E * 4);
    float* bufA   = (float*)carve((size_t)n * 128 * 4);
    float* bufB   = (float*)carve((size_t)n * 128 * 4);

    hipMemsetAsync(deg, 0, (size_t)n * 4, stream);

    int gE = (E + 255) / 256;
    int NB = (n + 1023) / 1024;  // 98 for n=100000 (<=128 required by k_scanB)

    k_count<<<gE, 256, 0, stream>>>(dst, E, deg);
    k_dinv<<<(n + 255) / 256, 256, 0, stream>>>(deg, dinv, n);
    k_scanA<<<NB, 256, 0, stream>>>(deg, n, bsum);
    k_scanB<<<1, 128, 0, stream>>>(bsum, NB);
    k_scanC<<<NB, 256, 0, stream>>>(deg, n, bsum, rowptr, cursor, E);
    k_fill<<<gE, 256, 0, stream>>>(src, dst, E, dinv, cursor, col, wnv);

    dim3 gg((n + 255) / 256, 2);
    // Layer 1
    k_gemm_xw<<<gg, 256, 0, stream>>>(x, W1, bufA, n);
    k_agg128<<<(n + 3) / 4, 256, 0, stream>>>(bufA, rowptr, col, wnv, dinv, b1, bufB, n);
    // Layer 2
    k_gemm_xw<<<gg, 256, 0, stream>>>(bufB, W2, bufA, n);
    k_agg128<<<(n + 3) / 4, 256, 0, stream>>>(bufA, rowptr, col, wnv, dinv, b2, bufB, n);
    // Layer 3 (F=8)
    k_gemm_w3<<<(n + 255) / 256, 256, 0, stream>>>(bufB, W3, bufA, n);
    k_agg8<<<(n * 8 + 255) / 256, 256, 0, stream>>>(bufA, rowptr, col, wnv, dinv, b3, bufB, n);
    // Classifier
    k_out<<<(n * 8 + 255) / 256, 256, 0, stream>>>(bufB, Wc, bc, (float*)d_out, n);
}